// Round 3
// baseline (823.907 us; speedup 1.0000x reference)
//
#include <hip/hip_runtime.h>
#include <cmath>

#define NB 64
#define ND 1024
#define DH 512
#define NL 2048
#define NCHUNK 16
#define RPB 128   // rows per block (L / NCHUNK)
#define RPW 32    // rows per wave
#define REC 520   // floats per (b,chunk,k) attn partial: [M, L, pad, pad, acc[512], pad]
#define KS 32     // GEMM k-split (4 blocks/CU -> 16 waves/CU latency hiding)

typedef float f4 __attribute__((ext_vector_type(4)));
__device__ __forceinline__ f4 ntld(const float* p) {
  return __builtin_nontemporal_load((const f4*)p);
}

// ---------------------------------------------------------------------------
// GEMM partials: part[ks][b][j] = sum_{k in slab} A[b][k] * W[j][k].
// A staged via LDS (coalesced float4, pad 36 keeps rows 16B-aligned). W rows
// wave-uniform -> scalar-load path. Block = 64 b x 32 j (4 waves x 8 j).
// Grid (32 j-tiles, KS). FUSE=1: last-arriving block of a j-tile's KS
// split-K blocks reduces the partials + tanh -> out (removes k_reduce<1>).
// ---------------------------------------------------------------------------
template <int KK, int FUSE>
__global__ __launch_bounds__(256, 4) void k_gemm(const float* __restrict__ A,
                                                 const float* __restrict__ W,
                                                 float* __restrict__ part,
                                                 float* __restrict__ out,
                                                 unsigned* __restrict__ cnt) {
  constexpr int SLAB = KK / KS;   // 32 (KK=1024) or 64 (KK=2048)
  __shared__ float As[64][36];
  const int t = threadIdx.x;
  const int lane = t & 63;
  const int wv = t >> 6;
  const int k0 = blockIdx.y * SLAB;
  const int j0 = __builtin_amdgcn_readfirstlane((int)(blockIdx.x * 32 + wv * 8));
  const float* Wb = W + (size_t)j0 * KK + k0;

  float acc[8];
#pragma unroll
  for (int j = 0; j < 8; j++) acc[j] = 0.f;

  const int srow = t >> 2, sko = (t & 3) * 8;
  const float* sbase = A + (size_t)srow * KK + k0 + sko;

  for (int kc = 0; kc < SLAB; kc += 32) {
    float4 v0 = *(const float4*)(sbase + kc);
    float4 v1 = *(const float4*)(sbase + kc + 4);
    __syncthreads();   // protect previous chunk's readers
    *(float4*)&As[srow][sko]     = v0;
    *(float4*)&As[srow][sko + 4] = v1;
    __syncthreads();
#pragma unroll
    for (int kk = 0; kk < 32; kk += 4) {
      float4 av = *(const float4*)&As[lane][kk];
      const float* wp = Wb + kc + kk;
#pragma unroll
      for (int j = 0; j < 8; j++) {
        float4 wq = *(const float4*)(wp + (size_t)j * KK);   // uniform -> s_load
        acc[j] = fmaf(av.x, wq.x, acc[j]);
        acc[j] = fmaf(av.y, wq.y, acc[j]);
        acc[j] = fmaf(av.z, wq.z, acc[j]);
        acc[j] = fmaf(av.w, wq.w, acc[j]);
      }
    }
  }
  float* p = part + ((size_t)blockIdx.y * 64 + lane) * ND + j0;
  *(float4*)(p)     = make_float4(acc[0], acc[1], acc[2], acc[3]);
  *(float4*)(p + 4) = make_float4(acc[4], acc[5], acc[6], acc[7]);

  if constexpr (FUSE) {
    // split-K last-block reduction (release partials, acq_rel counter)
    __threadfence();
    __shared__ unsigned lastS;
    if (t == 0)
      lastS = __hip_atomic_fetch_add(&cnt[blockIdx.x], 1u, __ATOMIC_ACQ_REL,
                                     __HIP_MEMORY_SCOPE_AGENT);
    __syncthreads();
    if (lastS != KS - 1) return;
    __threadfence();

    const int jt = blockIdx.x * 32;
    const int b = t >> 2, jj = (t & 3) * 8;
    const float* gp = part + (size_t)b * ND + jt + jj;
    float s[8];
#pragma unroll
    for (int x = 0; x < 8; x++) s[x] = 0.f;
#pragma unroll 4
    for (int ks = 0; ks < KS; ks++) {
      f4 v0 = *(const f4*)(gp + (size_t)ks * (64 * ND));
      f4 v1 = *(const f4*)(gp + (size_t)ks * (64 * ND) + 4);
      s[0] += v0.x; s[1] += v0.y; s[2] += v0.z; s[3] += v0.w;
      s[4] += v1.x; s[5] += v1.y; s[6] += v1.z; s[7] += v1.w;
    }
    float* op = out + (size_t)b * ND + jt + jj;
    *(float4*)(op)     = make_float4(tanhf(s[0]), tanhf(s[1]), tanhf(s[2]), tanhf(s[3]));
    *(float4*)(op + 4) = make_float4(tanhf(s[4]), tanhf(s[5]), tanhf(s[6]), tanhf(s[7]));
  }
}

// Sum KS partials -> target (no act). Also zeroes the 96 fusion counters
// (runs before both consumers; re-runs every iteration after ws poison).
__global__ __launch_bounds__(64) void k_reduce0(const float* __restrict__ part,
                                                float* __restrict__ outv,
                                                unsigned* __restrict__ cnt) {
  if (blockIdx.x == 0) {
    cnt[threadIdx.x] = 0;                       // [0..63]  attn per-b
    if (threadIdx.x < 32) cnt[64 + threadIdx.x] = 0;  // [64..95] gemm2 per-jtile
  }
  const int i = (blockIdx.x * 64 + threadIdx.x) * 4;
  float4 s = make_float4(0.f, 0.f, 0.f, 0.f);
#pragma unroll 8
  for (int ks = 0; ks < KS; ks++) {
    f4 v = ntld(part + (size_t)ks * (64 * ND) + i);
    s.x += v.x; s.y += v.y; s.z += v.z; s.w += v.w;
  }
  *(float4*)(outv + i) = s;
}

// ---------------------------------------------------------------------------
// Fused attention pass: context read ONCE (nontemporal — 256MB stream must
// not allocate through L2/L3; round-1 A/B showed cached loads cost ~20us).
// Hot loop identical to measured-best baseline. NEW: last-arriving block of
// each batch b performs the NCHUNK-merge + normalize (removes k3_combine).
// ---------------------------------------------------------------------------
__global__ __launch_bounds__(256, 4) void k2_attn(const float* __restrict__ ctx,
                                                  const float* __restrict__ tgt,
                                                  float* __restrict__ sc0,
                                                  float* __restrict__ sc1,
                                                  float* __restrict__ part,
                                                  float* __restrict__ combined,
                                                  const float* __restrict__ inp,
                                                  unsigned* __restrict__ cnt) {
  const int chunk = blockIdx.x, b = blockIdx.y;
  const int wave = threadIdx.x >> 6, lane = threadIdx.x & 63;
  const float* crow = ctx + ((size_t)b * NL + chunk * RPB + wave * RPW) * DH + lane * 8;

  // Lane owns d = 8*lane + j. target row interleaved (2d+k).
  float t0[8], t1[8];
  {
    const float* tp = tgt + b * ND + lane * 16;
#pragma unroll
    for (int j = 0; j < 4; j++) {
      float4 v = *(const float4*)(tp + j * 4);
      t0[2 * j] = v.x; t1[2 * j] = v.y; t0[2 * j + 1] = v.z; t1[2 * j + 1] = v.w;
    }
  }

  float m0 = -INFINITY, l0 = 0.f, m1 = -INFINITY, l1 = 0.f;
  float a0[8], a1[8];
#pragma unroll
  for (int j = 0; j < 8; j++) { a0[j] = 0.f; a1[j] = 0.f; }
  float sv0 = 0.f, sv1 = 0.f;

  f4 cur[4], nxt[4];   // 2 rows x 32B
  cur[0] = ntld(crow);
  cur[1] = ntld(crow + 4);
  cur[2] = ntld(crow + DH);
  cur[3] = ntld(crow + DH + 4);

#pragma unroll 2
  for (int ib = 0; ib < 16; ib++) {
    if (ib < 15) {
      const float* p = crow + (size_t)(2 * ib + 2) * DH;
      nxt[0] = ntld(p);
      nxt[1] = ntld(p + 4);
      nxt[2] = ntld(p + DH);
      nxt[3] = ntld(p + DH + 4);
    }
    const float* C = (const float*)cur;   // C[r*8+j], r in {0,1}

    float s0[2], s1[2];
#pragma unroll
    for (int r = 0; r < 2; r++) {
      float x0 = 0.f, x1 = 0.f;
#pragma unroll
      for (int j = 0; j < 8; j++) { x0 += C[r * 8 + j] * t0[j]; x1 += C[r * 8 + j] * t1[j]; }
      s0[r] = x0; s1[r] = x1;
    }
    // 4 independent butterfly chains (latency pipelined)
#pragma unroll
    for (int off = 32; off; off >>= 1) {
      s0[0] += __shfl_xor(s0[0], off);
      s0[1] += __shfl_xor(s0[1], off);
      s1[0] += __shfl_xor(s1[0], off);
      s1[1] += __shfl_xor(s1[1], off);
    }
#pragma unroll
    for (int r = 0; r < 2; r++)
      if (lane == 2 * ib + r) { sv0 = s0[r]; sv1 = s1[r]; }

    // k=0 amortized online-softmax update (branchless)
    {
      float mn = fmaxf(m0, fmaxf(s0[0], s0[1]));
      float al = __expf(m0 - mn);
      float p0 = __expf(s0[0] - mn), p1 = __expf(s0[1] - mn);
      l0 = l0 * al + p0 + p1;
      m0 = mn;
#pragma unroll
      for (int j = 0; j < 8; j++)
        a0[j] = a0[j] * al + p0 * C[j] + p1 * C[8 + j];
    }
    // k=1
    {
      float mn = fmaxf(m1, fmaxf(s1[0], s1[1]));
      float al = __expf(m1 - mn);
      float p0 = __expf(s1[0] - mn), p1 = __expf(s1[1] - mn);
      l1 = l1 * al + p0 + p1;
      m1 = mn;
#pragma unroll
      for (int j = 0; j < 8; j++)
        a1[j] = a1[j] * al + p0 * C[j] + p1 * C[8 + j];
    }
#pragma unroll
    for (int i = 0; i < 4; i++) cur[i] = nxt[i];
  }

  const int rowbase = b * NL + chunk * RPB + wave * RPW;
  if (lane < RPW) { sc0[rowbase + lane] = sv0; sc1[rowbase + lane] = sv1; }

  // merge 4 waves in LDS (epilogue, once per block: 4x ds_write_b128)
  __shared__ float accS[4][1024];
  __shared__ float mlS[4][4];
  *(float4*)&accS[wave][lane * 8]           = make_float4(a0[0], a0[1], a0[2], a0[3]);
  *(float4*)&accS[wave][lane * 8 + 4]       = make_float4(a0[4], a0[5], a0[6], a0[7]);
  *(float4*)&accS[wave][512 + lane * 8]     = make_float4(a1[0], a1[1], a1[2], a1[3]);
  *(float4*)&accS[wave][512 + lane * 8 + 4] = make_float4(a1[4], a1[5], a1[6], a1[7]);
  if (lane == 0) { mlS[wave][0] = m0; mlS[wave][1] = l0; mlS[wave][2] = m1; mlS[wave][3] = l1; }
  __syncthreads();

  const int t = threadIdx.x;
  const int k = (t * 4) >> 9;
  const int d = (t * 4) & 511;
  float M = fmaxf(fmaxf(mlS[0][2 * k], mlS[1][2 * k]), fmaxf(mlS[2][2 * k], mlS[3][2 * k]));
  float Lk = 0.f;
  float v0 = 0.f, v1 = 0.f, v2 = 0.f, v3 = 0.f;
#pragma unroll
  for (int w = 0; w < 4; w++) {
    float e = __expf(mlS[w][2 * k] - M);
    Lk += mlS[w][2 * k + 1] * e;
    const float* ap = &accS[w][k * 512 + d];
    v0 += ap[0] * e; v1 += ap[1] * e; v2 += ap[2] * e; v3 += ap[3] * e;
  }
  float* rec = part + ((size_t)(b * NCHUNK + chunk) * 2 + k) * REC;
  if ((t & 127) == 0) { rec[0] = M; rec[1] = Lk; }
  *(float4*)&rec[4 + d] = make_float4(v0, v1, v2, v3);

  // ---- last block of batch b: fused combine (was k3_combine) ----
  __threadfence();
  __shared__ unsigned lastS;
  if (t == 0)
    lastS = __hip_atomic_fetch_add(&cnt[b], 1u, __ATOMIC_ACQ_REL,
                                   __HIP_MEMORY_SCOPE_AGENT);
  __syncthreads();
  if (lastS != NCHUNK - 1) return;
  __threadfence();

  __shared__ float MM2[2], LL2[2];
  __shared__ float eS2[2][NCHUNK];
  if (t < 2) {
    const int kq = t;
    float Mk = -INFINITY;
#pragma unroll
    for (int c = 0; c < NCHUNK; c++)
      Mk = fmaxf(Mk, part[((size_t)(b * NCHUNK + c) * 2 + kq) * REC]);
    float Lq = 0.f;
#pragma unroll
    for (int c = 0; c < NCHUNK; c++) {
      const float* rc = part + ((size_t)(b * NCHUNK + c) * 2 + kq) * REC;
      Lq += rc[1] * __expf(rc[0] - Mk);
    }
    MM2[kq] = Mk; LL2[kq] = Lq;
  }
  __syncthreads();
  if (t < 2 * NCHUNK) {
    const int kq = t >> 4, c = t & 15;
    eS2[kq][c] = __expf(part[((size_t)(b * NCHUNK + c) * 2 + kq) * REC] - MM2[kq]);
  }
  __syncthreads();

  {
    const int kq = t >> 7, d0 = (t & 127) * 4;
    float vx = 0.f, vy = 0.f, vz = 0.f, vw = 0.f;
#pragma unroll
    for (int c = 0; c < NCHUNK; c++) {
      const f4 w = *(const f4*)(part + ((size_t)(b * NCHUNK + c) * 2 + kq) * REC + 4 + d0);
      const float e = eS2[kq][c];
      vx += w.x * e; vy += w.y * e; vz += w.z * e; vw += w.w * e;
    }
    const float invL = 1.f / LL2[kq];
    *(float4*)(combined + (size_t)b * 2048 + kq * 512 + d0) =
        make_float4(vx * invL, vy * invL, vz * invL, vw * invL);
  }
  *(float4*)(combined + (size_t)b * 2048 + 1024 + t * 4) =
      *(const float4*)(inp + (size_t)b * ND + t * 4);

  {
    const float M0 = MM2[0], i0 = 1.f / LL2[0];
    const float M1 = MM2[1], i1 = 1.f / LL2[1];
    const int pos = b * NL + t * 8;
    f4 xa = *(f4*)(sc0 + pos), xb = *(f4*)(sc0 + pos + 4);
    xa.x = __expf(xa.x - M0) * i0; xa.y = __expf(xa.y - M0) * i0;
    xa.z = __expf(xa.z - M0) * i0; xa.w = __expf(xa.w - M0) * i0;
    xb.x = __expf(xb.x - M0) * i0; xb.y = __expf(xb.y - M0) * i0;
    xb.z = __expf(xb.z - M0) * i0; xb.w = __expf(xb.w - M0) * i0;
    *(f4*)(sc0 + pos) = xa; *(f4*)(sc0 + pos + 4) = xb;
    f4 ya = *(f4*)(sc1 + pos), yb = *(f4*)(sc1 + pos + 4);
    ya.x = __expf(ya.x - M1) * i1; ya.y = __expf(ya.y - M1) * i1;
    ya.z = __expf(ya.z - M1) * i1; ya.w = __expf(ya.w - M1) * i1;
    yb.x = __expf(yb.x - M1) * i1; yb.y = __expf(yb.y - M1) * i1;
    yb.z = __expf(yb.z - M1) * i1; yb.w = __expf(yb.w - M1) * i1;
    *(f4*)(sc1 + pos) = ya; *(f4*)(sc1 + pos + 4) = yb;
  }
}

// ---------------------------------------------------------------------------
extern "C" void kernel_launch(void* const* d_in, const int* in_sizes, int n_in,
                              void* d_out, int out_size, void* d_ws, size_t ws_size,
                              hipStream_t stream) {
  const float* input   = (const float*)d_in[0];   // [64,1024]
  const float* context = (const float*)d_in[1];   // [64,2048,512]
  const float* W_in    = (const float*)d_in[2];   // [1024,1024]
  const float* W_out   = (const float*)d_in[3];   // [1024,2048]

  float* out   = (float*)d_out;        // [64,1024] contextOutput
  float* attn0 = out + NB * ND;        // [64,2048]
  float* attn1 = attn0 + NB * NL;      // [64,2048]

  float* ws       = (float*)d_ws;
  float* target   = ws;                               // 64*1024
  float* combined = target + NB * ND;                 // 64*2048
  float* apart    = combined + NB * 2048;             // 64*16*2*520
  float* gpart    = apart + NB * NCHUNK * 2 * REC;    // KS*64*1024
  unsigned* cnts  = (unsigned*)(gpart + (size_t)KS * 64 * ND);  // 96 counters

  // 1) target = input @ W_in.T (split-K partials; reduce also zeroes counters)
  k_gemm<ND, 0><<<dim3(32, KS), dim3(256), 0, stream>>>(input, W_in, gpart, nullptr, nullptr);
  k_reduce0<<<dim3(256), dim3(64), 0, stream>>>(gpart, target, cnts);
  // 2) fused scores + online-softmax partials + (last block per b) combine
  k2_attn<<<dim3(NCHUNK, NB), dim3(256), 0, stream>>>(context, target, attn0, attn1,
                                                      apart, combined, input, cnts);
  // 3) out = tanh(combined @ W_out.T) with fused last-block reduction
  k_gemm<2 * ND, 1><<<dim3(32, KS), dim3(256), 0, stream>>>(combined, W_out, gpart,
                                                            out, cnts + 64);
}

// Round 4
// 391.177 us; speedup vs baseline: 2.1062x; 2.1062x over previous
//
#include <hip/hip_runtime.h>
#include <cmath>

#define NB 64
#define ND 1024
#define DH 512
#define NL 2048
#define NCHUNK 16
#define RPB 128   // rows per block (L / NCHUNK)
#define RPW 32    // rows per wave
#define REC 520   // floats per (b,chunk,k) attn partial: [M, L, pad, pad, acc[512], pad]
#define KS 32     // GEMM k-split (4 blocks/CU -> 16 waves/CU latency hiding)

typedef float f4 __attribute__((ext_vector_type(4)));
__device__ __forceinline__ f4 ntld(const float* p) {
  return __builtin_nontemporal_load((const f4*)p);
}

// ---------------------------------------------------------------------------
// GEMM partials: part[ks][b][j] = sum_{k in slab} A[b][k] * W[j][k].
// A staged via LDS (coalesced float4, pad 36 keeps rows 16B-aligned). W rows
// are wave-uniform (all 64 lanes of a wave share the same 8 j) -> scalar-load
// path. Block = 64 b x 32 j (4 waves x 8 j). Grid (32 j-tiles, KS).
// NOTE (R3 post-mortem): do NOT fuse epilogues into this or k2_attn — the
// extra code perturbs regalloc of the hot loops (VGPR 95->64, spills, 7x).
// ---------------------------------------------------------------------------
template <int KK>
__global__ __launch_bounds__(256, 4) void k_gemm(const float* __restrict__ A,
                                                 const float* __restrict__ W,
                                                 float* __restrict__ part) {
  constexpr int SLAB = KK / KS;   // 32 (KK=1024) or 64 (KK=2048)
  __shared__ float As[64][36];
  const int t = threadIdx.x;
  const int lane = t & 63;
  const int wv = t >> 6;
  const int k0 = blockIdx.y * SLAB;
  const int j0 = __builtin_amdgcn_readfirstlane((int)(blockIdx.x * 32 + wv * 8));
  const float* Wb = W + (size_t)j0 * KK + k0;

  float acc[8];
#pragma unroll
  for (int j = 0; j < 8; j++) acc[j] = 0.f;

  const int srow = t >> 2, sko = (t & 3) * 8;
  const float* sbase = A + (size_t)srow * KK + k0 + sko;

  for (int kc = 0; kc < SLAB; kc += 32) {
    float4 v0 = *(const float4*)(sbase + kc);
    float4 v1 = *(const float4*)(sbase + kc + 4);
    __syncthreads();   // protect previous chunk's readers
    *(float4*)&As[srow][sko]     = v0;
    *(float4*)&As[srow][sko + 4] = v1;
    __syncthreads();
#pragma unroll
    for (int kk = 0; kk < 32; kk += 4) {
      float4 av = *(const float4*)&As[lane][kk];
      const float* wp = Wb + kc + kk;
#pragma unroll
      for (int j = 0; j < 8; j++) {
        float4 wq = *(const float4*)(wp + (size_t)j * KK);   // uniform -> s_load
        acc[j] = fmaf(av.x, wq.x, acc[j]);
        acc[j] = fmaf(av.y, wq.y, acc[j]);
        acc[j] = fmaf(av.z, wq.z, acc[j]);
        acc[j] = fmaf(av.w, wq.w, acc[j]);
      }
    }
  }
  float* p = part + ((size_t)blockIdx.y * 64 + lane) * ND + j0;
  *(float4*)(p)     = make_float4(acc[0], acc[1], acc[2], acc[3]);
  *(float4*)(p + 4) = make_float4(acc[4], acc[5], acc[6], acc[7]);
}

// Sum KS partials -> out, optional tanh. 64*1024 floats, grid 256 x 64.
// gpart is dead after this read -> nontemporal (no L2/L3 re-allocation).
template <int ACT>
__global__ __launch_bounds__(64) void k_reduce(const float* __restrict__ part,
                                               float* __restrict__ out) {
  const int i = (blockIdx.x * 64 + threadIdx.x) * 4;
  float4 s = make_float4(0.f, 0.f, 0.f, 0.f);
#pragma unroll 8
  for (int ks = 0; ks < KS; ks++) {
    f4 v = ntld(part + (size_t)ks * (64 * ND) + i);
    s.x += v.x; s.y += v.y; s.z += v.z; s.w += v.w;
  }
  if (ACT) { s.x = tanhf(s.x); s.y = tanhf(s.y); s.z = tanhf(s.z); s.w = tanhf(s.w); }
  *(float4*)(out + i) = s;
}

// ---------------------------------------------------------------------------
// Fused attention pass: context read ONCE (nontemporal — 256MB stream must
// not allocate through L2/L3; round-1 A/B showed cached loads cost ~20us).
// Batch-2 rows per step (4 independent butterfly chains), depth-2-row
// register prefetch. Unconditional rescale: branchless hot loop keeps the
// compiler's load pipelining intact (round-1 deferred-rescale regressed).
// ~95 VGPRs -> no spill at launch_bounds(256,4) (16 waves/CU).
// ---------------------------------------------------------------------------
__global__ __launch_bounds__(256, 4) void k2_attn(const float* __restrict__ ctx,
                                                  const float* __restrict__ tgt,
                                                  float* __restrict__ sc0,
                                                  float* __restrict__ sc1,
                                                  float* __restrict__ part) {
  const int chunk = blockIdx.x, b = blockIdx.y;
  const int wave = threadIdx.x >> 6, lane = threadIdx.x & 63;
  const float* crow = ctx + ((size_t)b * NL + chunk * RPB + wave * RPW) * DH + lane * 8;

  // Lane owns d = 8*lane + j. target row interleaved (2d+k).
  float t0[8], t1[8];
  {
    const float* tp = tgt + b * ND + lane * 16;
#pragma unroll
    for (int j = 0; j < 4; j++) {
      float4 v = *(const float4*)(tp + j * 4);
      t0[2 * j] = v.x; t1[2 * j] = v.y; t0[2 * j + 1] = v.z; t1[2 * j + 1] = v.w;
    }
  }

  float m0 = -INFINITY, l0 = 0.f, m1 = -INFINITY, l1 = 0.f;
  float a0[8], a1[8];
#pragma unroll
  for (int j = 0; j < 8; j++) { a0[j] = 0.f; a1[j] = 0.f; }
  float sv0 = 0.f, sv1 = 0.f;

  f4 cur[4], nxt[4];   // 2 rows x 32B
  cur[0] = ntld(crow);
  cur[1] = ntld(crow + 4);
  cur[2] = ntld(crow + DH);
  cur[3] = ntld(crow + DH + 4);

#pragma unroll 2
  for (int ib = 0; ib < 16; ib++) {
    if (ib < 15) {
      const float* p = crow + (size_t)(2 * ib + 2) * DH;
      nxt[0] = ntld(p);
      nxt[1] = ntld(p + 4);
      nxt[2] = ntld(p + DH);
      nxt[3] = ntld(p + DH + 4);
    }
    const float* C = (const float*)cur;   // C[r*8+j], r in {0,1}

    float s0[2], s1[2];
#pragma unroll
    for (int r = 0; r < 2; r++) {
      float x0 = 0.f, x1 = 0.f;
#pragma unroll
      for (int j = 0; j < 8; j++) { x0 += C[r * 8 + j] * t0[j]; x1 += C[r * 8 + j] * t1[j]; }
      s0[r] = x0; s1[r] = x1;
    }
    // 4 independent butterfly chains (latency pipelined)
#pragma unroll
    for (int off = 32; off; off >>= 1) {
      s0[0] += __shfl_xor(s0[0], off);
      s0[1] += __shfl_xor(s0[1], off);
      s1[0] += __shfl_xor(s1[0], off);
      s1[1] += __shfl_xor(s1[1], off);
    }
#pragma unroll
    for (int r = 0; r < 2; r++)
      if (lane == 2 * ib + r) { sv0 = s0[r]; sv1 = s1[r]; }

    // k=0 amortized online-softmax update (branchless)
    {
      float mn = fmaxf(m0, fmaxf(s0[0], s0[1]));
      float al = __expf(m0 - mn);
      float p0 = __expf(s0[0] - mn), p1 = __expf(s0[1] - mn);
      l0 = l0 * al + p0 + p1;
      m0 = mn;
#pragma unroll
      for (int j = 0; j < 8; j++)
        a0[j] = a0[j] * al + p0 * C[j] + p1 * C[8 + j];
    }
    // k=1
    {
      float mn = fmaxf(m1, fmaxf(s1[0], s1[1]));
      float al = __expf(m1 - mn);
      float p0 = __expf(s1[0] - mn), p1 = __expf(s1[1] - mn);
      l1 = l1 * al + p0 + p1;
      m1 = mn;
#pragma unroll
      for (int j = 0; j < 8; j++)
        a1[j] = a1[j] * al + p0 * C[j] + p1 * C[8 + j];
    }
#pragma unroll
    for (int i = 0; i < 4; i++) cur[i] = nxt[i];
  }

  const int rowbase = b * NL + chunk * RPB + wave * RPW;
  if (lane < RPW) { sc0[rowbase + lane] = sv0; sc1[rowbase + lane] = sv1; }

  // merge 4 waves in LDS (epilogue, once per block: 4x ds_write_b128)
  __shared__ float accS[4][1024];
  __shared__ float mlS[4][4];
  *(float4*)&accS[wave][lane * 8]           = make_float4(a0[0], a0[1], a0[2], a0[3]);
  *(float4*)&accS[wave][lane * 8 + 4]       = make_float4(a0[4], a0[5], a0[6], a0[7]);
  *(float4*)&accS[wave][512 + lane * 8]     = make_float4(a1[0], a1[1], a1[2], a1[3]);
  *(float4*)&accS[wave][512 + lane * 8 + 4] = make_float4(a1[4], a1[5], a1[6], a1[7]);
  if (lane == 0) { mlS[wave][0] = m0; mlS[wave][1] = l0; mlS[wave][2] = m1; mlS[wave][3] = l1; }
  __syncthreads();

  const int t = threadIdx.x;
  const int k = (t * 4) >> 9;
  const int d = (t * 4) & 511;
  float M = fmaxf(fmaxf(mlS[0][2 * k], mlS[1][2 * k]), fmaxf(mlS[2][2 * k], mlS[3][2 * k]));
  float Lk = 0.f;
  float v0 = 0.f, v1 = 0.f, v2 = 0.f, v3 = 0.f;
#pragma unroll
  for (int w = 0; w < 4; w++) {
    float e = __expf(mlS[w][2 * k] - M);
    Lk += mlS[w][2 * k + 1] * e;
    const float* ap = &accS[w][k * 512 + d];
    v0 += ap[0] * e; v1 += ap[1] * e; v2 += ap[2] * e; v3 += ap[3] * e;
  }
  float* rec = part + ((size_t)(b * NCHUNK + chunk) * 2 + k) * REC;
  if ((t & 127) == 0) { rec[0] = M; rec[1] = Lk; }
  *(float4*)&rec[4 + d] = make_float4(v0, v1, v2, v3);
}

// ---------------------------------------------------------------------------
// Merge NCHUNK attn partials -> combined row [w0|w1|input]; normalize raw
// scores in place. Grid 256 = 64 b x 4 quadrants.
// ---------------------------------------------------------------------------
__global__ __launch_bounds__(256) void k3_combine(const float* __restrict__ part,
                                                  const float* __restrict__ inp,
                                                  float* __restrict__ combined,
                                                  float* __restrict__ sc0,
                                                  float* __restrict__ sc1) {
  const int b = blockIdx.x >> 2, q = blockIdx.x & 3;
  const int t = threadIdx.x;
  __shared__ float MM[2], LL[2];
  __shared__ float eS[2][NCHUNK];
  if (t < 2) {
    const int k = t;
    float Mk = -INFINITY;
#pragma unroll
    for (int c = 0; c < NCHUNK; c++)
      Mk = fmaxf(Mk, part[((size_t)(b * NCHUNK + c) * 2 + k) * REC]);
    float Lk = 0.f;
#pragma unroll
    for (int c = 0; c < NCHUNK; c++) {
      const float* rec = part + ((size_t)(b * NCHUNK + c) * 2 + k) * REC;
      Lk += rec[1] * __expf(rec[0] - Mk);
    }
    MM[k] = Mk; LL[k] = Lk;
  }
  __syncthreads();
  if (t < 2 * NCHUNK) {
    const int k = t >> 4, c = t & 15;
    eS[k][c] = __expf(part[((size_t)(b * NCHUNK + c) * 2 + k) * REC] - MM[k]);
  }
  __syncthreads();

  const int k = t >> 7, d = q * 128 + (t & 127);
  float v = 0.f;
#pragma unroll
  for (int c = 0; c < NCHUNK; c++)
    v += part[((size_t)(b * NCHUNK + c) * 2 + k) * REC + 4 + d] * eS[k][c];
  combined[(size_t)b * 2048 + k * 512 + d] = v / LL[k];

  combined[(size_t)b * 2048 + 1024 + q * 256 + t] = inp[(size_t)b * ND + q * 256 + t];

  const float M0 = MM[0], i0 = 1.f / LL[0];
  const float M1 = MM[1], i1 = 1.f / LL[1];
  const int pos = b * NL + q * 512 + t * 2;
  float2 x0 = *(const float2*)(sc0 + pos);
  float2 x1 = *(const float2*)(sc1 + pos);
  x0.x = __expf(x0.x - M0) * i0; x0.y = __expf(x0.y - M0) * i0;
  x1.x = __expf(x1.x - M1) * i1; x1.y = __expf(x1.y - M1) * i1;
  *(float2*)(sc0 + pos) = x0;
  *(float2*)(sc1 + pos) = x1;
}

// ---------------------------------------------------------------------------
extern "C" void kernel_launch(void* const* d_in, const int* in_sizes, int n_in,
                              void* d_out, int out_size, void* d_ws, size_t ws_size,
                              hipStream_t stream) {
  const float* input   = (const float*)d_in[0];   // [64,1024]
  const float* context = (const float*)d_in[1];   // [64,2048,512]
  const float* W_in    = (const float*)d_in[2];   // [1024,1024]
  const float* W_out   = (const float*)d_in[3];   // [1024,2048]

  float* out   = (float*)d_out;        // [64,1024] contextOutput
  float* attn0 = out + NB * ND;        // [64,2048]
  float* attn1 = attn0 + NB * NL;      // [64,2048]

  float* ws       = (float*)d_ws;
  float* target   = ws;                               // 64*1024
  float* combined = target + NB * ND;                 // 64*2048
  float* apart    = combined + NB * 2048;             // 64*16*2*520
  float* gpart    = apart + NB * NCHUNK * 2 * REC;    // KS*64*1024

  // 1) target = input @ W_in.T   (split-K partials + reduce)
  k_gemm<ND><<<dim3(32, KS), dim3(256), 0, stream>>>(input, W_in, gpart);
  k_reduce<0><<<dim3(256), dim3(64), 0, stream>>>(gpart, target);
  // 2) fused scores + online-softmax weighted partials (context read once)
  k2_attn<<<dim3(NCHUNK, NB), dim3(256), 0, stream>>>(context, target, attn0, attn1, apart);
  // 3) merge partials -> combined rows; normalize attn in place
  k3_combine<<<dim3(4 * NB), dim3(256), 0, stream>>>(apart, input, combined, attn0, attn1);
  // 4) out = tanh(combined @ W_out.T)
  k_gemm<2 * ND><<<dim3(32, KS), dim3(256), 0, stream>>>(combined, W_out, gpart);
  k_reduce<1><<<dim3(256), dim3(64), 0, stream>>>(gpart, out);
}